// Round 5
// baseline (1110.918 us; speedup 1.0000x reference)
//
#include <hip/hip_runtime.h>
#include <hip/hip_fp16.h>

// Problem constants (b=8, s=4096, EMBED=1024, HEADS=16, HEAD_DIM=64)
#define NTOK 32768
#define NE   1024

typedef _Float16 half_t;
typedef _Float16 f16x8 __attribute__((ext_vector_type(8)));
typedef _Float16 f16x4 __attribute__((ext_vector_type(4)));
typedef float    f32x4 __attribute__((ext_vector_type(4)));

typedef __attribute__((address_space(1))) const unsigned int guint;
typedef __attribute__((address_space(3))) unsigned int luint;

__device__ __forceinline__ void async16(const void* g, void* l) {
    __builtin_amdgcn_global_load_lds((guint*)g, (luint*)l, 16, 0, 0);
}

// ---------------------------------------------------------------- convert
__global__ __launch_bounds__(256) void cvt_f32_f16(const float* __restrict__ s,
                                                   half_t* __restrict__ d, int n) {
    int i = (blockIdx.x * 256 + threadIdx.x) * 8;
    if (i >= n) return;
    float4 a = *(const float4*)(s + i);
    float4 b = *(const float4*)(s + i + 4);
    f16x8 h = {(_Float16)a.x, (_Float16)a.y, (_Float16)a.z, (_Float16)a.w,
               (_Float16)b.x, (_Float16)b.y, (_Float16)b.z, (_Float16)b.w};
    *(f16x8*)(d + i) = h;
}

// all four 1024x1024 weights in one launch (y = matrix index)
__global__ __launch_bounds__(256) void cvt4_f32_f16(const float* __restrict__ s0,
                                                    const float* __restrict__ s1,
                                                    const float* __restrict__ s2,
                                                    const float* __restrict__ s3,
                                                    half_t* __restrict__ d) {
    const float* srcs[4] = {s0, s1, s2, s3};
    const float* s = srcs[blockIdx.y];
    int i = (blockIdx.x * 256 + threadIdx.x) * 8;
    float4 a = *(const float4*)(s + i);
    float4 b = *(const float4*)(s + i + 4);
    f16x8 h = {(_Float16)a.x, (_Float16)a.y, (_Float16)a.z, (_Float16)a.w,
               (_Float16)b.x, (_Float16)b.y, (_Float16)b.z, (_Float16)b.w};
    *(f16x8*)(d + (size_t)blockIdx.y * (NE * NE) + i) = h;
}

// ---------------------------------------------------------------- GEMM C = A * B^T
// R8: revert R7's B-from-global regression (MfmaUtil 28%, gather-bound) back
// to R5's LDS-staged A+B (measured best, 43%/220us), then remove the per-round
// pipeline drains with PERSISTENT blocks (grid=256, 1/CU by 128 KiB LDS):
//  - each block loops over ITERS tiles; the uniform K-loop stages the NEXT
//    iteration's tile 0 at t=14, so next-tile prologue latency hides under
//    the current tile's last phases + epilogue, and the epilogue store drain
//    overlaps next-tile staging (no s_endpgm drain between tiles).
//  - epilogue uses buf1 only (64 KB, sweeps) and lgkm-only barriers (BARL),
//    never __syncthreads (which drains vmcnt and would kill the prefetch).
//  - leaner uniform K-tile: 4 barriers + 3 counted waits (was 8 + 4):
//      P0: stage b0(t+2); MMA q00; WAITV(12); BAR; read bF1
//      P1: stage a0(t+2); MMA q01; WAITV(12); BAR; read aF1
//      P2: stage b1(t+2); MMA q11
//      P3: MMA q10; WAITV(10); BAR; read aF0,bF0(t+1); stage a1(t+2); BAR
//    Every stage->retire >= 5 phases; every slot re-stage is barrier-
//    separated from its last cross-wave read (audited per slot).

#define WAITV(N) asm volatile("s_waitcnt vmcnt(" #N ")" ::: "memory")
#define BAR()                                  \
    do {                                       \
        asm volatile("" ::: "memory");         \
        __builtin_amdgcn_s_barrier();          \
        asm volatile("" ::: "memory");         \
    } while (0)
#define BARL()                                             \
    do {                                                   \
        asm volatile("s_waitcnt lgkmcnt(0)" ::: "memory"); \
        __builtin_amdgcn_s_barrier();                      \
        asm volatile("" ::: "memory");                     \
    } while (0)

#define ASC(b, c) (Asm + ((b) * 2 + (c)) * 8192)
#define BSC(b, c) (Bsm + ((b) * 2 + (c)) * 8192)

// stage one A-chunk q at col k0 from matrix P into LDS chunk dst (16 KiB).
// phys row = l*64 + rr  <->  logical A row = l*128 + q*64 + rr
#define STAGE_A(P, dst, q, k0)                                                \
    do {                                                                      \
        _Pragma("unroll") for (int l = 0; l < 2; ++l)                         \
            async16((P) + (size_t)(l * 128 + (q) * 64 + rr) * K + (k0) + cc,  \
                    (char*)(dst) + l * 8192 + w * 1024);                      \
    } while (0)

// stage one B-chunk r: phys row = l*64 + rr  <->  logical B col-row =
// (l*2 + wb)*64 + r*32 + (rr&31)
#define STAGE_B(P, dst, r, k0)                                                \
    do {                                                                      \
        _Pragma("unroll") for (int l = 0; l < 2; ++l)                         \
            async16((P) + (size_t)((l * 2 + wb) * 64 + (r) * 32 + (rr & 31)) * K + \
                        (k0) + cc,                                            \
                    (char*)(dst) + l * 8192 + w * 1024);                      \
    } while (0)

// read the 8 A frags (4 mt x 2 kk) of chunk q (buffer b) for this wave
#define READ_A(dstf, b, q)                                                    \
    do {                                                                      \
        _Pragma("unroll") for (int i = 0; i < 4; ++i)                         \
        _Pragma("unroll") for (int x = 0; x < 2; ++x)                         \
            dstf[i][x] = *(const f16x8*)&ASC(b, q)[(wr * 64 + i * 16 + l16) * 64 + \
                                                   (((x * 4 + quad) ^ sw) * 8)]; \
    } while (0)

// read the 4 B frags (2 nt x 2 kk) of chunk r (buffer b) for this wave
#define READ_B(dstf, b, r)                                                    \
    do {                                                                      \
        _Pragma("unroll") for (int i2 = 0; i2 < 2; ++i2)                      \
        _Pragma("unroll") for (int x = 0; x < 2; ++x)                         \
            dstf[i2][x] = *(const f16x8*)&BSC(b, r)[(wc * 32 + i2 * 16 + l16) * 64 + \
                                                    (((x * 4 + quad) ^ sw) * 8)]; \
    } while (0)

// one quadrant: 16 MFMAs into acc[QA*4+i][RB*2+jj]
#define MMA(af, bf, QA, RB)                                                   \
    do {                                                                      \
        __builtin_amdgcn_s_setprio(1);                                        \
        _Pragma("unroll") for (int i = 0; i < 4; ++i)                         \
        _Pragma("unroll") for (int jj = 0; jj < 2; ++jj)                      \
        _Pragma("unroll") for (int x = 0; x < 2; ++x)                         \
            acc[(QA) * 4 + i][(RB) * 2 + jj] =                                \
                __builtin_amdgcn_mfma_f32_16x16x32_f16(                       \
                    af[i][x], bf[jj][x], acc[(QA) * 4 + i][(RB) * 2 + jj], 0, 0, 0); \
        __builtin_amdgcn_s_setprio(0);                                        \
    } while (0)

template <bool QKV>
__global__ __launch_bounds__(512, 2) void gemm_bt(const half_t* __restrict__ A,
                                                  const half_t* __restrict__ Bbase,
                                                  void* __restrict__ Cout,
                                                  const float* __restrict__ theta) {
    constexpr int K     = 1024;
    constexpr int J     = QKV ? 12 : 4;  // (z, xt) blocks per m-tile
    constexpr int ITERS = QKV ? 6 : 2;   // persistent: tiles per block
    __shared__ alignas(16) half_t smem[65536];  // 128 KiB
    half_t* Asm = smem;
    half_t* Bsm = smem + 32768;

    const int id  = blockIdx.x;
    const int xcd = id & 7;

    const int tid  = threadIdx.x;
    const int w    = tid >> 6;
    const int lane = tid & 63;
    const int quad = lane >> 4;
    const int l16  = lane & 15;
    const int sw   = l16 & 7;
    const int wr   = w >> 2, wc = w & 3;  // 2 x 4 waves, each 128x64 of C

    const int rr = tid >> 3;                     // staging row within 64-group
    const int cc = ((tid & 7) ^ (rr & 7)) * 8;   // XOR-pre-swizzled source col
    const int wb = tid >> 8;                     // B col-row bit

    auto decode = [&](int v, const half_t*& Agp, const half_t*& Bgp,
                      size_t& m0o, int& n0o, int& zso) {
        const int slot = v >> 3;
        const int yg   = slot / J;
        const int jx   = slot - yg * J;
        const int mt   = yg * 8 + xcd;
        zso = QKV ? (jx >> 2) : 0;
        const int xtt = QKV ? (jx & 3) : jx;
        m0o = (size_t)mt * 256;
        n0o = xtt * 256;
        Agp = A + m0o * K;
        Bgp = Bbase + (size_t)zso * (size_t)(NE * NE) + (size_t)n0o * K;
    };

    f16x8 aF0[4][2], aF1[4][2], bF0[2][2], bF1[2][2];
    f32x4 acc[8][4];

    for (int it = 0; it < ITERS; ++it) {
        const bool more = (it + 1 < ITERS);
        const half_t *Ag, *Bg, *Agn = nullptr, *Bgn = nullptr;
        size_t m0, m0n;
        int n0, zsl, n0n, zn;
        decode(id + it * 256, Ag, Bg, m0, n0, zsl);
        if (more) decode(id + (it + 1) * 256, Agn, Bgn, m0n, n0n, zn);

#pragma unroll
        for (int i = 0; i < 8; ++i)
#pragma unroll
            for (int jj = 0; jj < 4; ++jj) acc[i][jj] = (f32x4){0.f, 0.f, 0.f, 0.f};

        // pre-loop: (it==0) stage tile0 into buf0; stage tile1 into buf1.
        // For it>0, tile0 was staged at t=14 of the previous iteration.
        if (it == 0) {
            STAGE_B(Bg, BSC(0, 0), 0, 0);
            STAGE_A(Ag, ASC(0, 0), 0, 0);
            STAGE_B(Bg, BSC(0, 1), 1, 0);
            STAGE_A(Ag, ASC(0, 1), 1, 0);
        }
        STAGE_B(Bg, BSC(1, 0), 0, 64);
        STAGE_A(Ag, ASC(1, 0), 0, 64);
        STAGE_B(Bg, BSC(1, 1), 1, 64);
        STAGE_A(Ag, ASC(1, 1), 1, 64);
        WAITV(8);  // retire tile0 (+ all older stores from prev epilogue)
        BAR();
        READ_A(aF0, 0, 0);
        READ_B(bF0, 0, 0);
        BAR();  // reads done before P0(0) re-stages BSC(0,0)

        for (int t = 0; t < 14; ++t) {
            const int cur = t & 1, nxt = cur ^ 1;
            const int kf = (t + 2) * 64;
            // P0
            STAGE_B(Bg, BSC(cur, 0), 0, kf);
            MMA(aF0, bF0, 0, 0);
            WAITV(12);  // retire b1(t)
            BAR();
            READ_B(bF1, cur, 1);
            // P1
            STAGE_A(Ag, ASC(cur, 0), 0, kf);
            MMA(aF0, bF1, 0, 1);
            WAITV(12);  // retire a1(t)
            BAR();
            READ_A(aF1, cur, 1);
            // P2
            STAGE_B(Bg, BSC(cur, 1), 1, kf);
            MMA(aF1, bF1, 1, 1);
            // P3
            MMA(aF1, bF0, 1, 0);
            WAITV(10);  // retire b0(t+1), a0(t+1)
            BAR();
            READ_A(aF0, nxt, 0);
            READ_B(bF0, nxt, 0);
            STAGE_A(Ag, ASC(cur, 1), 1, kf);
            BAR();  // reads done before P0(t+1) re-stages
        }
        // t = 14 (cur = 0): stages target NEXT iteration's tile 0 (k0 = 0)
        if (more) {
            STAGE_B(Bgn, BSC(0, 0), 0, 0);
            MMA(aF0, bF0, 0, 0);
            WAITV(12);
            BAR();
            READ_B(bF1, 0, 1);
            STAGE_A(Agn, ASC(0, 0), 0, 0);
            MMA(aF0, bF1, 0, 1);
            WAITV(12);
            BAR();
            READ_A(aF1, 0, 1);
            STAGE_B(Bgn, BSC(0, 1), 1, 0);
            MMA(aF1, bF1, 1, 1);
            MMA(aF1, bF0, 1, 0);
            WAITV(10);
            BAR();
            READ_A(aF0, 1, 0);
            READ_B(bF0, 1, 0);
            STAGE_A(Agn, ASC(0, 1), 1, 0);
            BAR();
            // t = 15 (cur = 1): no stages
            MMA(aF0, bF0, 0, 0);
            WAITV(10);  // retire b1(15) (younger: a1(15) + 4 next-tile chunks)
            BAR();
            READ_B(bF1, 1, 1);
            MMA(aF0, bF1, 0, 1);
            WAITV(8);   // retire a1(15)
            BAR();
            READ_A(aF1, 1, 1);
            MMA(aF1, bF1, 1, 1);
            MMA(aF1, bF0, 1, 0);
        } else {
            // final iteration: t = 14 with no stages, counted drain
            MMA(aF0, bF0, 0, 0);
            WAITV(10);  // retire b1(14)
            BAR();
            READ_B(bF1, 0, 1);
            MMA(aF0, bF1, 0, 1);
            WAITV(8);   // retire a1(14)
            BAR();
            READ_A(aF1, 0, 1);
            MMA(aF1, bF1, 1, 1);
            MMA(aF1, bF0, 1, 0);
            WAITV(4);   // retire b0(15), a0(15)
            BAR();
            READ_A(aF0, 1, 0);
            READ_B(bF0, 1, 0);
            // t = 15
            MMA(aF0, bF0, 0, 0);
            WAITV(2);
            BAR();
            READ_B(bF1, 1, 1);
            MMA(aF0, bF1, 0, 1);
            WAITV(0);
            BAR();
            READ_A(aF1, 1, 1);
            MMA(aF1, bF1, 1, 1);
            MMA(aF1, bF0, 1, 0);
        }

        // ---- epilogue in buf1 only (64 KB); buf0 holds next tile's data.
        // lgkm-only barriers: do NOT drain vmcnt (next-tile loads in flight).
        BARL();  // all waves' buf1 frag reads complete
        half_t* Ep0 = Asm + 16384;  // As buf1, 32 KB
        half_t* Ep1 = Bsm + 16384;  // Bs buf1, 32 KB

        if (QKV) {
            half_t* Cg = (half_t*)Cout + (size_t)zsl * ((size_t)NTOK * NE);
#pragma unroll
            for (int s = 0; s < 2; ++s) {
                if (wr == s) {
#pragma unroll
                    for (int nt = 0; nt < 4; ++nt) {
                        const int col = wc * 64 + nt * 16 + l16;
                        const float th = theta[col & 63];
#pragma unroll
                        for (int mt = 0; mt < 8; ++mt) {
#pragma unroll
                            for (int r4 = 0; r4 < 4; ++r4) {
                                const int r = mt * 16 + quad * 4 + r4;
                                half_t* piece = (r < 64) ? Ep0 : Ep1;
                                piece[(r & 63) * 256 +
                                      (col ^ (((r >> 2) & 3) << 4))] =
                                    (half_t)__cosf(acc[mt][nt][r4] + th);
                            }
                        }
                    }
                }
                BARL();
#pragma unroll
                for (int itx = 0; itx < 8; ++itx) {
                    const int row = itx * 16 + (tid >> 5);
                    const int seg = tid & 31;
                    const half_t* piece = (row < 64) ? Ep0 : Ep1;
                    f16x8 vv = *(const f16x8*)&piece[(row & 63) * 256 +
                                                     ((seg * 8) ^ (((row >> 2) & 3) << 4))];
                    *(f16x8*)&Cg[(m0 + s * 128 + row) * NE + n0 + seg * 8] = vv;
                }
                BARL();
            }
        } else {
            float* Cg  = (float*)Cout;
            float* Fp0 = (float*)Ep0;
            float* Fp1 = (float*)Ep1;
#pragma unroll
            for (int s = 0; s < 4; ++s) {
                if (wr == (s >> 1)) {
#pragma unroll
                    for (int nt = 0; nt < 4; ++nt) {
                        const int col = wc * 64 + nt * 16 + l16;
#pragma unroll
                        for (int m = 0; m < 4; ++m) {
                            const int mt = (s & 1) * 4 + m;
#pragma unroll
                            for (int r4 = 0; r4 < 4; ++r4) {
                                const int r = m * 16 + quad * 4 + r4;
                                float* piece = (r < 32) ? Fp0 : Fp1;
                                piece[(r & 31) * 256 +
                                      (col ^ (((r >> 2) & 1) << 4))] = acc[mt][nt][r4];
                            }
                        }
                    }
                }
                BARL();
#pragma unroll
                for (int itx = 0; itx < 8; ++itx) {
                    const int row = itx * 8 + (tid >> 6);
                    const int seg = tid & 63;
                    const float* piece = (row < 32) ? Fp0 : Fp1;
                    f32x4 vv = *(const f32x4*)&piece[(row & 31) * 256 +
                                                     ((seg * 4) ^ (((row >> 2) & 1) << 4))];
                    *(f32x4*)&Cg[(m0 + s * 64 + row) * NE + n0 + seg * 4] = vv;
                }
                BARL();
            }
        }
        // next iteration's pre-loop stages into buf1 follow the last BARL.
    }
}

// ---------------------------------------------------------------- MFMA attention
// One wave = one token, 4 tokens/block. Scores S[16x16] = q.k^T over d=64 via
// two 16x16x32 MFMAs; q/k fragments loaded DIRECTLY from global in A/B layout
// [m|n = lane&15][k = quad*8+j] (m120-verified). Softmax rows (=quad*4+r in
// C-layout) reduced with 16-wide shuffle butterflies. PV via four 16x16x16
// MFMAs: P and v^T round-trip LDS with stride 20 (conflict-free).
__global__ __launch_bounds__(256) void attn_kernel(const half_t* __restrict__ q,
                                                   const half_t* __restrict__ k,
                                                   const half_t* __restrict__ v,
                                                   half_t* __restrict__ out) {
    __shared__ half_t vT[4][64][20];  // [wave][d][head j], pad->20
    __shared__ half_t Pl[4][16][20];  // [wave][i][j], pad->20
    const int tid  = threadIdx.x;
    const int w    = tid >> 6;
    const int lane = tid & 63;
    const int quad = lane >> 4;
    const int l16  = lane & 15;
    const size_t base = ((size_t)blockIdx.x * 4 + w) * 1024;

    // stage v transposed: lane covers head h = lane>>2, d-chunk (lane&3)*16
    {
        const int h = lane >> 2, d0 = (lane & 3) * 16;
        f16x8 va = *(const f16x8*)(v + base + h * 64 + d0);
        f16x8 vb = *(const f16x8*)(v + base + h * 64 + d0 + 8);
#pragma unroll
        for (int z = 0; z < 8; ++z) {
            vT[w][d0 + z][h]     = va[z];
            vT[w][d0 + 8 + z][h] = vb[z];
        }
    }

    // scores: frags straight from global (no LDS)
    f16x8 aq0 = *(const f16x8*)(q + base + l16 * 64 + quad * 8);
    f16x8 aq1 = *(const f16x8*)(q + base + l16 * 64 + 32 + quad * 8);
    f16x8 bk0 = *(const f16x8*)(k + base + l16 * 64 + quad * 8);
    f16x8 bk1 = *(const f16x8*)(k + base + l16 * 64 + 32 + quad * 8);
    f32x4 S = __builtin_amdgcn_mfma_f32_16x16x32_f16(aq0, bk0, (f32x4){0.f,0.f,0.f,0.f}, 0, 0, 0);
    S = __builtin_amdgcn_mfma_f32_16x16x32_f16(aq1, bk1, S, 0, 0, 0);

    // softmax over cols (l16) per row (quad*4+r); write P f16 to LDS
#pragma unroll
    for (int r = 0; r < 4; ++r) {
        float s = S[r] * 0.125f;  // 1/sqrt(64)
        float mx = s;
#pragma unroll
        for (int o = 8; o; o >>= 1) mx = fmaxf(mx, __shfl_xor(mx, o));
        float e = __expf(s - mx);
        float sum = e;
#pragma unroll
        for (int o = 8; o; o >>= 1) sum += __shfl_xor(sum, o);
        Pl[w][quad * 4 + r][l16] = (half_t)(e / sum);
    }
    __syncthreads();  // vT + Pl visible across lanes

    // PV: A = P [m=i][k=j], B = v^T [k=j][n=d], 4 d-chunks of 16
    f16x4 ap = *(const f16x4*)&Pl[w][l16][quad * 4];
#pragma unroll
    for (int c = 0; c < 4; ++c) {
        f16x4 bv = *(const f16x4*)&vT[w][c * 16 + l16][quad * 4];
        f32x4 O = __builtin_amdgcn_mfma_f32_16x16x16f16(ap, bv, (f32x4){0.f,0.f,0.f,0.f}, 0, 0, 0);
#pragma unroll
        for (int r = 0; r < 4; ++r)
            out[base + (quad * 4 + r) * 64 + c * 16 + l16] = (half_t)O[r];
    }
}

// ---------------------------------------------------------------- launch
extern "C" void kernel_launch(void* const* d_in, const int* in_sizes, int n_in,
                              void* d_out, int out_size, void* d_ws, size_t ws_size,
                              hipStream_t stream) {
    // setup_inputs order: x, Wk, Wq, Wv, Wo, theta
    const float* x     = (const float*)d_in[0];
    const float* Wk    = (const float*)d_in[1];
    const float* Wq    = (const float*)d_in[2];
    const float* Wv    = (const float*)d_in[3];
    const float* Wo    = (const float*)d_in[4];
    const float* theta = (const float*)d_in[5];

    char* ws = (char*)d_ws;
    half_t* xh  = (half_t*)ws;                           // 64 MB (reused for attn_out)
    half_t* wh  = (half_t*)(ws + (size_t)(64 << 20));    // 8 MB: Wq,Wk,Wv,Wo f16
    half_t* qkv = (half_t*)(ws + (size_t)(72 << 20));    // 192 MB: q_q,k_q,v_q f16

    cvt_f32_f16<<<NTOK * NE / 2048, 256, 0, stream>>>(x, xh, NTOK * NE);
    cvt4_f32_f16<<<dim3(NE * NE / 2048, 4), 256, 0, stream>>>(Wq, Wk, Wv, Wo, wh);

    // q,k,v projections + cos(.+theta): persistent, 256 blocks x 6 tiles
    gemm_bt<true><<<256, 512, 0, stream>>>(xh, wh, qkv, theta);

    // per-token attention over heads (4 tokens/block)
    attn_kernel<<<NTOK / 4, 256, 0, stream>>>(qkv, qkv + (size_t)NTOK * NE,
                                              qkv + 2 * (size_t)NTOK * NE, xh);

    // out = attn_out @ Wo^T: persistent, 256 blocks x 2 tiles
    gemm_bt<false><<<256, 512, 0, stream>>>(xh, wh + 3 * NE * NE, d_out, nullptr);
}

// Round 6
// 554.042 us; speedup vs baseline: 2.0051x; 2.0051x over previous
//
#include <hip/hip_runtime.h>
#include <hip/hip_fp16.h>

// Problem constants (b=8, s=4096, EMBED=1024, HEADS=16, HEAD_DIM=64)
#define NTOK 32768
#define NE   1024

typedef _Float16 half_t;
typedef _Float16 f16x8 __attribute__((ext_vector_type(8)));
typedef _Float16 f16x4 __attribute__((ext_vector_type(4)));
typedef float    f32x4 __attribute__((ext_vector_type(4)));

typedef __attribute__((address_space(1))) const unsigned int guint;
typedef __attribute__((address_space(3))) unsigned int luint;

__device__ __forceinline__ void async16(const void* g, void* l) {
    __builtin_amdgcn_global_load_lds((guint*)g, (luint*)l, 16, 0, 0);
}

// ---------------------------------------------------------------- convert
__global__ __launch_bounds__(256) void cvt_f32_f16(const float* __restrict__ s,
                                                   half_t* __restrict__ d, int n) {
    int i = (blockIdx.x * 256 + threadIdx.x) * 8;
    if (i >= n) return;
    float4 a = *(const float4*)(s + i);
    float4 b = *(const float4*)(s + i + 4);
    f16x8 h = {(_Float16)a.x, (_Float16)a.y, (_Float16)a.z, (_Float16)a.w,
               (_Float16)b.x, (_Float16)b.y, (_Float16)b.z, (_Float16)b.w};
    *(f16x8*)(d + i) = h;
}

// all four 1024x1024 weights in one launch (y = matrix index)
__global__ __launch_bounds__(256) void cvt4_f32_f16(const float* __restrict__ s0,
                                                    const float* __restrict__ s1,
                                                    const float* __restrict__ s2,
                                                    const float* __restrict__ s3,
                                                    half_t* __restrict__ d) {
    const float* srcs[4] = {s0, s1, s2, s3};
    const float* s = srcs[blockIdx.y];
    int i = (blockIdx.x * 256 + threadIdx.x) * 8;
    float4 a = *(const float4*)(s + i);
    float4 b = *(const float4*)(s + i + 4);
    f16x8 h = {(_Float16)a.x, (_Float16)a.y, (_Float16)a.z, (_Float16)a.w,
               (_Float16)b.x, (_Float16)b.y, (_Float16)b.z, (_Float16)b.w};
    *(f16x8*)(d + (size_t)blockIdx.y * (NE * NE) + i) = h;
}

// ---------------------------------------------------------------- GEMM C = A * B^T
// R9 = R5 verbatim (the measured-best structure: 558.8 us total, QKV 220 us,
// MfmaUtil 43%, FETCH 189 MB, WRITE 196 MB). Post-R6/R7/R8 ablations proved
// every piece load-bearing:
//  - launch-per-round (not persistent): HW dispatcher keeps the 12 A-tile L2
//    sharers co-resident AND time-aligned; persistent blocks drift -> full
//    A re-fetch (R8: FETCH 822 MB, 3.2x slower).
//  - B staged in LDS (not global->reg): B-frag gather is 16-line/instr and
//    exposes raw latency (R7: MfmaUtil 28%).
//  - 3-phase stage->retire depth is sufficient; deeper is neutral (R6).
// Schedule per K-tile: HK-ordered phases, ds_reads at end of phase p-1
// (latency hides under barrier), frags double-buffered, WAITV(4-ish) counted
// waits, LDS-coalesced epilogue through the dead 128 KiB LDS.

#define WAITV(N) asm volatile("s_waitcnt vmcnt(" #N ")" ::: "memory")
#define BARRIER()                              \
    do {                                       \
        asm volatile("" ::: "memory");         \
        __builtin_amdgcn_s_barrier();          \
        asm volatile("" ::: "memory");         \
    } while (0)

#define ASC(b, c) (Asm + ((b) * 2 + (c)) * 8192)
#define BSC(b, c) (Bsm + ((b) * 2 + (c)) * 8192)

// stage one A-chunk q of K-tile at col k0 into LDS chunk dst (16 KiB).
// phys row = l*64 + rr  <->  logical A row = l*128 + q*64 + rr
#define STAGE_A(dst, q, k0)                                                   \
    do {                                                                      \
        _Pragma("unroll") for (int l = 0; l < 2; ++l)                         \
            async16(Ag + (size_t)(l * 128 + (q) * 64 + rr) * K + (k0) + cc,   \
                    (char*)(dst) + l * 8192 + w * 1024);                      \
    } while (0)

// stage one B-chunk r: phys row = l*64 + rr  <->  logical B col-row =
// (l*2 + wb)*64 + r*32 + (rr&31)
#define STAGE_B(dst, r, k0)                                                   \
    do {                                                                      \
        _Pragma("unroll") for (int l = 0; l < 2; ++l)                         \
            async16(Bg + (size_t)((l * 2 + wb) * 64 + (r) * 32 + (rr & 31)) * K + \
                        (k0) + cc,                                            \
                    (char*)(dst) + l * 8192 + w * 1024);                      \
    } while (0)

// read the 8 A frags (4 mt x 2 kk) of chunk q (buffer b) for this wave
#define READ_A(dstf, b, q)                                                    \
    do {                                                                      \
        _Pragma("unroll") for (int i = 0; i < 4; ++i)                         \
        _Pragma("unroll") for (int x = 0; x < 2; ++x)                         \
            dstf[i][x] = *(const f16x8*)&ASC(b, q)[(wr * 64 + i * 16 + l16) * 64 + \
                                                   (((x * 4 + quad) ^ sw) * 8)]; \
    } while (0)

// read the 4 B frags (2 nt x 2 kk) of chunk r (buffer b) for this wave
#define READ_B(dstf, b, r)                                                    \
    do {                                                                      \
        _Pragma("unroll") for (int i2 = 0; i2 < 2; ++i2)                      \
        _Pragma("unroll") for (int x = 0; x < 2; ++x)                         \
            dstf[i2][x] = *(const f16x8*)&BSC(b, r)[(wc * 32 + i2 * 16 + l16) * 64 + \
                                                    (((x * 4 + quad) ^ sw) * 8)]; \
    } while (0)

// one quadrant: 16 MFMAs into acc[QA*4+i][RB*2+jj]
#define MMA(af, bf, QA, RB)                                                   \
    do {                                                                      \
        __builtin_amdgcn_s_setprio(1);                                        \
        _Pragma("unroll") for (int i = 0; i < 4; ++i)                         \
        _Pragma("unroll") for (int jj = 0; jj < 2; ++jj)                      \
        _Pragma("unroll") for (int x = 0; x < 2; ++x)                         \
            acc[(QA) * 4 + i][(RB) * 2 + jj] =                                \
                __builtin_amdgcn_mfma_f32_16x16x32_f16(                       \
                    af[i][x], bf[jj][x], acc[(QA) * 4 + i][(RB) * 2 + jj], 0, 0, 0); \
        __builtin_amdgcn_s_setprio(0);                                        \
    } while (0)

template <bool QKV>
__global__ __launch_bounds__(512, 2) void gemm_bt(const half_t* __restrict__ A,
                                                  const half_t* __restrict__ Bbase,
                                                  void* __restrict__ Cout,
                                                  const float* __restrict__ theta) {
    constexpr int K  = 1024;
    constexpr int NT = 16;             // K / 64 K-tiles
    constexpr int J  = QKV ? 12 : 4;   // (z, xt) blocks per m-tile
    __shared__ alignas(16) half_t smem[65536];  // 128 KiB
    half_t* Asm = smem;
    half_t* Bsm = smem + 32768;

    const int id    = blockIdx.x;
    const int xcd   = id & 7;
    const int slot  = id >> 3;
    const int ygrp  = slot / J;
    const int j     = slot - ygrp * J;
    const int mtile = ygrp * 8 + xcd;
    const int zsl   = QKV ? (j >> 2) : 0;
    const int xt    = QKV ? (j & 3) : j;

    const int tid  = threadIdx.x;
    const int w    = tid >> 6;
    const int lane = tid & 63;
    const int quad = lane >> 4;
    const int l16  = lane & 15;
    const int sw   = l16 & 7;
    const int wr   = w >> 2, wc = w & 3;  // 2 x 4 waves, each 128x64 of C
    const size_t m0 = (size_t)mtile * 256;
    const int    n0 = xt * 256;

    const half_t* Ag = A + m0 * K;
    const half_t* Bg = Bbase + (size_t)zsl * (size_t)(NE * NE) + (size_t)n0 * K;

    const int rr = tid >> 3;                     // staging row within 64-group
    const int cc = ((tid & 7) ^ (rr & 7)) * 8;   // XOR-pre-swizzled source col
    const int wb = tid >> 8;                     // B col-row bit

    f32x4 acc[8][4];
#pragma unroll
    for (int i = 0; i < 8; ++i)
#pragma unroll
        for (int jj = 0; jj < 4; ++jj) acc[i][jj] = (f32x4){0.f, 0.f, 0.f, 0.f};

    // prologue: 5 chunks issued; retire first two; read first quadrant frags
    STAGE_A(ASC(0, 0), 0, 0);    // A0(0)
    STAGE_B(BSC(0, 0), 0, 0);    // B0(0)
    STAGE_B(BSC(0, 1), 1, 0);    // B1(0)
    STAGE_A(ASC(0, 1), 1, 0);    // A1(0)
    STAGE_A(ASC(1, 0), 0, 64);   // A0(1)
    WAITV(6);                    // retire A0(0), B0(0)
    BARRIER();

    f16x8 aF0[4][2], aF1[4][2], bF0[2][2], bF1[2][2];
    READ_A(aF0, 0, 0);
    READ_B(bF0, 0, 0);
    // invariant before P0(t): outstanding = {B1(t), A1(t), A0(t+1)} = 6 loads

    for (int t = 0; t < NT - 1; ++t) {
        const int cur = t & 1, nxt = cur ^ 1;
        const int kn = (t + 1) * 64;
        // P0: MFMA (A0,B0); stage B0(t+1); read bF1 for P1
        WAITV(4);                 // retire B1(t)
        BARRIER();
        STAGE_B(BSC(nxt, 0), 0, kn);
        MMA(aF0, bF0, 0, 0);
        READ_B(bF1, cur, 1);
        BARRIER();
        // P1: MFMA (A0,B1); stage B1(t+1); read aF1 for P2
        WAITV(4);                 // retire A1(t)
        BARRIER();
        STAGE_B(BSC(nxt, 1), 1, kn);
        MMA(aF0, bF1, 0, 1);
        READ_A(aF1, cur, 1);
        BARRIER();
        // P2: MFMA (A1,B1); stage A1(t+1); no read (aF1,bF0 live)
        WAITV(4);                 // retire A0(t+1) (read at P3 end)
        BARRIER();
        STAGE_A(ASC(nxt, 1), 1, kn);
        MMA(aF1, bF1, 1, 1);
        BARRIER();
        // P3: MFMA (A1,B0); stage A0(t+2); read aF0,bF0 of tile t+1
        WAITV(4);                 // retire B0(t+1)
        BARRIER();
        if (t + 2 < NT) STAGE_A(ASC(cur, 0), 0, kn + 64);
        MMA(aF1, bF0, 1, 0);
        READ_A(aF0, nxt, 0);
        READ_B(bF0, nxt, 0);
        BARRIER();
    }
    // t = NT-1 peeled: outstanding = {B1(15), A1(15)} = 4 loads
    {
        WAITV(2);                 // retire B1(15)
        BARRIER();
        MMA(aF0, bF0, 0, 0);
        READ_B(bF1, 1, 1);
        BARRIER();
        WAITV(0);                 // retire A1(15)
        BARRIER();
        MMA(aF0, bF1, 0, 1);
        READ_A(aF1, 1, 1);
        BARRIER();
        MMA(aF1, bF1, 1, 1);
        MMA(aF1, bF0, 1, 0);
    }
    __syncthreads();  // LDS now dead -> reuse for coalesced C staging

    // C/D layout: col = lane&15, row = quad*4 + reg  [m89]
    if (QKV) {
        // stage cos(acc+theta) as f16 [256][256] in LDS with bank-XOR
        // (col ^ (quad<<4): quads hit 4 distinct 8-bank blocks -> 2-way, free)
        half_t* Cl = smem;
#pragma unroll
        for (int nt = 0; nt < 4; ++nt) {
            const int col = wc * 64 + nt * 16 + l16;
            const float th = theta[col & 63];
#pragma unroll
            for (int mt = 0; mt < 8; ++mt) {
                const int rowb = wr * 128 + mt * 16 + quad * 4;
#pragma unroll
                for (int r = 0; r < 4; ++r) {
                    const int row = rowb + r;
                    Cl[row * 256 + (col ^ (((row >> 2) & 3) << 4))] =
                        (half_t)__cosf(acc[mt][nt][r] + th);
                }
            }
        }
        __syncthreads();
        half_t* Cg = (half_t*)Cout + (size_t)zsl * ((size_t)NTOK * NE);
#pragma unroll
        for (int it = 0; it < 16; ++it) {
            const int row = it * 16 + (tid >> 5);
            const int seg = tid & 31;
            f16x8 vv = *(const f16x8*)&Cl[row * 256 +
                                          ((seg * 8) ^ (((row >> 2) & 3) << 4))];
            *(f16x8*)&Cg[(m0 + row) * NE + n0 + seg * 8] = vv;  // 512 B / 32 lanes
        }
    } else {
        // f32 out: two 128-row sweeps through LDS [128][256] f32
        float* ClF = (float*)smem;
        float* Cg  = (float*)Cout;
#pragma unroll
        for (int s = 0; s < 2; ++s) {
            if (wr == s) {
#pragma unroll
                for (int nt = 0; nt < 4; ++nt) {
                    const int col = wc * 64 + nt * 16 + l16;
#pragma unroll
                    for (int mt = 0; mt < 8; ++mt) {
                        const int rowb = mt * 16 + quad * 4;
#pragma unroll
                        for (int r = 0; r < 4; ++r) {
                            const int row = rowb + r;
                            ClF[row * 256 + (col ^ (((row >> 2) & 1) << 4))] =
                                acc[mt][nt][r];
                        }
                    }
                }
            }
            __syncthreads();
#pragma unroll
            for (int it = 0; it < 16; ++it) {
                const int row = it * 8 + (tid >> 6);
                const int seg = tid & 63;
                f32x4 vv = *(const f32x4*)&ClF[row * 256 +
                                               ((seg * 4) ^ (((row >> 2) & 1) << 4))];
                *(f32x4*)&Cg[(m0 + s * 128 + row) * NE + n0 + seg * 4] = vv;
            }
            __syncthreads();
        }
    }
}

// ---------------------------------------------------------------- MFMA attention
// R9: 8 tokens/block (512 threads, 4096 blocks; was 4/256/8192) — per-wave
// code unchanged, only the w range and LDS outer dim double. One wave = one
// token. Scores S[16x16] = q.k^T over d=64 via two 16x16x32 MFMAs; q/k frags
// straight from global in A/B layout [m|n = lane&15][k = quad*8+j]. Softmax
// rows reduced with 16-wide shuffle butterflies. PV via four 16x16x16 MFMAs:
// P and v^T round-trip LDS with stride 20 (conflict-free).
__global__ __launch_bounds__(512) void attn_kernel(const half_t* __restrict__ q,
                                                   const half_t* __restrict__ k,
                                                   const half_t* __restrict__ v,
                                                   half_t* __restrict__ out) {
    __shared__ half_t vT[8][64][20];  // [wave][d][head j], pad->20
    __shared__ half_t Pl[8][16][20];  // [wave][i][j], pad->20
    const int tid  = threadIdx.x;
    const int w    = tid >> 6;
    const int lane = tid & 63;
    const int quad = lane >> 4;
    const int l16  = lane & 15;
    const size_t base = ((size_t)blockIdx.x * 8 + w) * 1024;

    // stage v transposed: lane covers head h = lane>>2, d-chunk (lane&3)*16
    {
        const int h = lane >> 2, d0 = (lane & 3) * 16;
        f16x8 va = *(const f16x8*)(v + base + h * 64 + d0);
        f16x8 vb = *(const f16x8*)(v + base + h * 64 + d0 + 8);
#pragma unroll
        for (int z = 0; z < 8; ++z) {
            vT[w][d0 + z][h]     = va[z];
            vT[w][d0 + 8 + z][h] = vb[z];
        }
    }

    // scores: frags straight from global (no LDS)
    f16x8 aq0 = *(const f16x8*)(q + base + l16 * 64 + quad * 8);
    f16x8 aq1 = *(const f16x8*)(q + base + l16 * 64 + 32 + quad * 8);
    f16x8 bk0 = *(const f16x8*)(k + base + l16 * 64 + quad * 8);
    f16x8 bk1 = *(const f16x8*)(k + base + l16 * 64 + 32 + quad * 8);
    f32x4 S = __builtin_amdgcn_mfma_f32_16x16x32_f16(aq0, bk0, (f32x4){0.f,0.f,0.f,0.f}, 0, 0, 0);
    S = __builtin_amdgcn_mfma_f32_16x16x32_f16(aq1, bk1, S, 0, 0, 0);

    // softmax over cols (l16) per row (quad*4+r); write P f16 to LDS
#pragma unroll
    for (int r = 0; r < 4; ++r) {
        float s = S[r] * 0.125f;  // 1/sqrt(64)
        float mx = s;
#pragma unroll
        for (int o = 8; o; o >>= 1) mx = fmaxf(mx, __shfl_xor(mx, o));
        float e = __expf(s - mx);
        float sum = e;
#pragma unroll
        for (int o = 8; o; o >>= 1) sum += __shfl_xor(sum, o);
        Pl[w][quad * 4 + r][l16] = (half_t)(e / sum);
    }
    __syncthreads();  // vT + Pl visible across lanes

    // PV: A = P [m=i][k=j], B = v^T [k=j][n=d], 4 d-chunks of 16
    f16x4 ap = *(const f16x4*)&Pl[w][l16][quad * 4];
#pragma unroll
    for (int c = 0; c < 4; ++c) {
        f16x4 bv = *(const f16x4*)&vT[w][c * 16 + l16][quad * 4];
        f32x4 O = __builtin_amdgcn_mfma_f32_16x16x16f16(ap, bv, (f32x4){0.f,0.f,0.f,0.f}, 0, 0, 0);
#pragma unroll
        for (int r = 0; r < 4; ++r)
            out[base + (quad * 4 + r) * 64 + c * 16 + l16] = (half_t)O[r];
    }
}

// ---------------------------------------------------------------- launch
extern "C" void kernel_launch(void* const* d_in, const int* in_sizes, int n_in,
                              void* d_out, int out_size, void* d_ws, size_t ws_size,
                              hipStream_t stream) {
    // setup_inputs order: x, Wk, Wq, Wv, Wo, theta
    const float* x     = (const float*)d_in[0];
    const float* Wk    = (const float*)d_in[1];
    const float* Wq    = (const float*)d_in[2];
    const float* Wv    = (const float*)d_in[3];
    const float* Wo    = (const float*)d_in[4];
    const float* theta = (const float*)d_in[5];

    char* ws = (char*)d_ws;
    half_t* xh  = (half_t*)ws;                           // 64 MB (reused for attn_out)
    half_t* wh  = (half_t*)(ws + (size_t)(64 << 20));    // 8 MB: Wq,Wk,Wv,Wo f16
    half_t* qkv = (half_t*)(ws + (size_t)(72 << 20));    // 192 MB: q_q,k_q,v_q f16

    cvt_f32_f16<<<NTOK * NE / 2048, 256, 0, stream>>>(x, xh, NTOK * NE);
    cvt4_f32_f16<<<dim3(NE * NE / 2048, 4), 256, 0, stream>>>(Wq, Wk, Wv, Wo, wh);

    // q,k,v projections + cos(.+theta): 8 xcd * 16 ygrp * 12 (z,x); 256x256 tiles
    gemm_bt<true><<<1536, 512, 0, stream>>>(xh, wh, qkv, theta);

    // per-token attention over heads (8 tokens/block)
    attn_kernel<<<NTOK / 8, 512, 0, stream>>>(qkv, qkv + (size_t)NTOK * NE,
                                              qkv + 2 * (size_t)NTOK * NE, xh);

    // out = attn_out @ Wo^T: 8 xcd * 16 ygrp * 4 xt
    gemm_bt<false><<<512, 512, 0, stream>>>(xh, wh + 3 * NE * NE, d_out, nullptr);
}